// Round 2
// baseline (147.530 us; speedup 1.0000x reference)
//
#include <hip/hip_runtime.h>

// Problem constants (from reference setup_inputs)
constexpr int Bx = 8;
constexpr int Nn = 16384;   // power of two -> shift/mask index math
constexpr int Vv = 12;
constexpr long long TOT = (long long)Bx * Nn * Vv;   // 1,572,864 output elems
constexpr int NB1 = (Bx * Nn) / 256;                 // 512 blocks
constexpr unsigned TAG = 0x5CA1AB1Eu;                // non-repeating-byte magic

__device__ __forceinline__ float lk(float x) { return fmaxf(x, 0.2f * x); }

// Single fused kernel, PLAIN launch + software grid barrier.
// Co-residency guarantee: __launch_bounds__(256,4) -> VGPR<=128 -> 4 waves/SIMD
// -> 4 blocks/CU -> capacity 1024 blocks on 256 CUs; grid is 512. No deadlock.
//
// Phase 1: compute 12 pre-BN y values into registers; block-reduce (sum,sumsq)
//          -> part[bid]; threadfence; agent-scope store TAG -> flags[bid].
// Barrier: all threads spin (agent-scope acquire loads) until all 512 flags==TAG.
//          TAG is written fresh every graph replay (harness re-poisons ws), and
//          a repeated-byte/word poison pattern cannot equal TAG's byte sequence.
// Phase 2: every block redundantly reduces the 512 partials (agent-scope loads,
//          L2-resident), derives BN coefficients, applies BN + leaky to the
//          register-held y and stores the final output ONCE.
__global__ __launch_bounds__(256, 4) void nlmp_fused(
    const float* __restrict__ F,
    const float* __restrict__ W1, const float* __restrict__ b1,
    const float* __restrict__ W2, const float* __restrict__ b2,
    const float* __restrict__ W3, const float* __restrict__ b3,
    const float* __restrict__ cw, const float* __restrict__ cb,
    const float* __restrict__ gamma, const float* __restrict__ beta,
    float* __restrict__ y, float* __restrict__ part, unsigned* __restrict__ flags)
{
    const int t = blockIdx.x * blockDim.x + threadIdx.x;  // in [0, B*N)

    // tiny weight set: broadcast loads, L2/L1 cached
    const float w100 = W1[0], w101 = W1[1], w110 = W1[2], w111 = W1[3];
    const float bb10 = b1[0], bb11 = b1[1];
    const float w200 = W2[0], w201 = W2[1], w210 = W2[2], w211 = W2[3];
    const float bb20 = b2[0], bb21 = b2[1];
    const float w30 = W3[0], w31 = W3[1], bb3 = b3[0];
    const float c0 = cw[0], c1 = cw[1], cbv = cb[0];

    // F[b,n,0..11]: contiguous 48 B -> three float4 loads
    float f[Vv];
    const float4* fp = reinterpret_cast<const float4*>(F + (long long)t * Vv);
    float4 q0 = fp[0], q1 = fp[1], q2 = fp[2];
    f[0] = q0.x; f[1] = q0.y; f[2]  = q0.z; f[3]  = q0.w;
    f[4] = q1.x; f[5] = q1.y; f[6]  = q1.z; f[7]  = q1.w;
    f[8] = q2.x; f[9] = q2.y; f[10] = q2.z; f[11] = q2.w;

    // Layer-1 factored: h[c](i,j) = lk( W1[c,0]*F[j] + (W1[c,1]*F[i] + b1[c]) )
    // a0/a1 arrays (inner-loop j); p0/p1 as per-i scalars (register pressure).
    float a0[Vv], a1[Vv];
#pragma unroll
    for (int v = 0; v < Vv; ++v) {
        a0[v] = w100 * f[v];
        a1[v] = w110 * f[v];
    }

    float yr[Vv];                 // pre-BN y, kept in registers across the barrier
    float s = 0.f, ss = 0.f;
#pragma unroll
    for (int i = 0; i < Vv; ++i) {
        const float p0i = fmaf(w101, f[i], bb10);
        const float p1i = fmaf(w111, f[i], bb11);
        float ms = 0.f;
#pragma unroll
        for (int j = 0; j < Vv; ++j) {
            float h0 = lk(a0[j] + p0i);
            float h1 = lk(a1[j] + p1i);
            float g0 = lk(fmaf(w200, h0, fmaf(w201, h1, bb20)));
            float g1 = lk(fmaf(w210, h0, fmaf(w211, h1, bb21)));
            ms += lk(fmaf(w30, g0, fmaf(w31, g1, bb3)));
        }
        float yv = fmaf(c0, f[i], fmaf(c1, ms, cbv));
        yr[i] = yv;
        s += yv;
        ss = fmaf(yv, yv, ss);
    }

    // wave(64) shuffle reduction, then block reduction
#pragma unroll
    for (int off = 32; off > 0; off >>= 1) {
        s  += __shfl_down(s,  off, 64);
        ss += __shfl_down(ss, off, 64);
    }
    __shared__ float ls[4], lss[4];
    __shared__ float coef[3];   // scale, mean, shift
    const int lane = threadIdx.x & 63;
    const int wave = threadIdx.x >> 6;
    if (lane == 0) { ls[wave] = s; lss[wave] = ss; }
    __syncthreads();
    if (threadIdx.x == 0) {
        part[2 * blockIdx.x]     = ls[0]  + ls[1]  + ls[2]  + ls[3];
        part[2 * blockIdx.x + 1] = lss[0] + lss[1] + lss[2] + lss[3];
        __threadfence();  // device-scope release of part before flag
        __hip_atomic_store(&flags[blockIdx.x], TAG,
                           __ATOMIC_RELEASE, __HIP_MEMORY_SCOPE_AGENT);
    }

    // ---- software grid barrier: thread t watches flags[t] and flags[t+256]
    while (__hip_atomic_load(&flags[threadIdx.x],
                             __ATOMIC_ACQUIRE, __HIP_MEMORY_SCOPE_AGENT) != TAG) {}
    while (__hip_atomic_load(&flags[threadIdx.x + 256],
                             __ATOMIC_ACQUIRE, __HIP_MEMORY_SCOPE_AGENT) != TAG) {}
    __syncthreads();

    // ---- phase 2: redundant all-block reduction of the 512 partials.
    // Agent-scope loads bypass any stale per-CU L1 line from a prior replay.
    {
        float rs, rss;
        {
            float pax = __hip_atomic_load(&part[2 * threadIdx.x],
                                          __ATOMIC_RELAXED, __HIP_MEMORY_SCOPE_AGENT);
            float pay = __hip_atomic_load(&part[2 * threadIdx.x + 1],
                                          __ATOMIC_RELAXED, __HIP_MEMORY_SCOPE_AGENT);
            float pbx = __hip_atomic_load(&part[2 * (threadIdx.x + 256)],
                                          __ATOMIC_RELAXED, __HIP_MEMORY_SCOPE_AGENT);
            float pby = __hip_atomic_load(&part[2 * (threadIdx.x + 256) + 1],
                                          __ATOMIC_RELAXED, __HIP_MEMORY_SCOPE_AGENT);
            rs  = pax + pbx;
            rss = pay + pby;
        }
#pragma unroll
        for (int off = 32; off > 0; off >>= 1) {
            rs  += __shfl_down(rs,  off, 64);
            rss += __shfl_down(rss, off, 64);
        }
        if (lane == 0) { ls[wave] = rs; lss[wave] = rss; }
        __syncthreads();
        if (threadIdx.x == 0) {
            double S  = (double)ls[0]  + ls[1]  + ls[2]  + ls[3];
            double SS = (double)lss[0] + lss[1] + lss[2] + lss[3];
            double mean = S / (double)TOT;
            double var  = SS / (double)TOT - mean * mean;
            coef[0] = (float)(1.0 / sqrt(var + 1e-5)) * gamma[0];
            coef[1] = (float)mean;
            coef[2] = beta[0];
        }
        __syncthreads();
    }
    const float scale = coef[0], mb = coef[1], bt = coef[2];

    const int b = t >> 14;        // / 16384
    const int n = t & (Nn - 1);
#pragma unroll
    for (int i = 0; i < Vv; ++i) {
        // coalesced per i across n; single store pass, post-BN
        y[((long long)b * Vv + i) * Nn + n] = lk(fmaf(yr[i] - mb, scale, bt));
    }
}

extern "C" void kernel_launch(void* const* d_in, const int* in_sizes, int n_in,
                              void* d_out, int out_size, void* d_ws, size_t ws_size,
                              hipStream_t stream) {
    const float* F  = (const float*)d_in[0];
    const float* W1 = (const float*)d_in[1];
    const float* b1 = (const float*)d_in[2];
    const float* W2 = (const float*)d_in[3];
    const float* b2 = (const float*)d_in[4];
    const float* W3 = (const float*)d_in[5];
    const float* b3 = (const float*)d_in[6];
    const float* cw = (const float*)d_in[7];
    const float* cb = (const float*)d_in[8];
    const float* gamma = (const float*)d_in[9];
    const float* beta  = (const float*)d_in[10];

    float* out = (float*)d_out;                        // final output, written once
    float* part = (float*)d_ws;                        // 512 x (sum,sumsq) = 4 KB
    unsigned* flags = (unsigned*)((char*)d_ws + 4096); // 512 barrier flags

    nlmp_fused<<<NB1, 256, 0, stream>>>(
        F, W1, b1, W2, b2, W3, b3, cw, cb, gamma, beta, out, part, flags);
}

// Round 3
// 104.140 us; speedup vs baseline: 1.4167x; 1.4167x over previous
//
#include <hip/hip_runtime.h>

// Problem constants (from reference setup_inputs)
constexpr int Bx = 8;
constexpr int Nn = 16384;   // power of two -> shift/mask index math
constexpr int Vv = 12;
constexpr long long TOT = (long long)Bx * Nn * Vv;   // 1,572,864 output elems
constexpr int NB1 = (Bx * Nn) / 256;                 // 512 blocks
constexpr unsigned TAG = 0x5CA1AB1Eu;                // non-repeating-byte magic
constexpr unsigned long long TAG2 = 0x5CA1AB1E5CA1AB1EULL;

__device__ __forceinline__ float lk(float x) { return fmaxf(x, 0.2f * x); }

// Single fused kernel, plain launch + HIERARCHICAL software grid barrier.
// Round-2 post-mortem: all-to-all spin (512 blocks x 512 flags, acquire loads
// with per-iteration cache invalidates) caused a fabric queueing collapse ->
// 77us kernel. v3: block 0 wave 0 aggregates the 512 arrival flags (relaxed
// u64 loads, 256/round) and release-stores ONE DONE flag; all other blocks
// poll only that flag with relaxed loads (1 coalesced line request per wave
// per ~600cy). One __threadfence() after poll success provides the acquire.
//
// Co-residency: __launch_bounds__(256,4) -> <=128 VGPR -> 4 blocks/CU capacity,
// grid 512 on 256 CUs (2/CU). Proven by round 2 (passed; no deadlock).
__global__ __launch_bounds__(256, 4) void nlmp_fused(
    const float* __restrict__ F,
    const float* __restrict__ W1, const float* __restrict__ b1,
    const float* __restrict__ W2, const float* __restrict__ b2,
    const float* __restrict__ W3, const float* __restrict__ b3,
    const float* __restrict__ cw, const float* __restrict__ cb,
    const float* __restrict__ gamma, const float* __restrict__ beta,
    float* __restrict__ y, float* __restrict__ part, unsigned* __restrict__ flags)
{
    const int t = blockIdx.x * blockDim.x + threadIdx.x;  // in [0, B*N)

    // tiny weight set: broadcast loads, L2/L1 cached
    const float w100 = W1[0], w101 = W1[1], w110 = W1[2], w111 = W1[3];
    const float bb10 = b1[0], bb11 = b1[1];
    const float w200 = W2[0], w201 = W2[1], w210 = W2[2], w211 = W2[3];
    const float bb20 = b2[0], bb21 = b2[1];
    const float w30 = W3[0], w31 = W3[1], bb3 = b3[0];
    const float c0 = cw[0], c1 = cw[1], cbv = cb[0];

    // F[b,n,0..11]: contiguous 48 B -> three float4 loads
    float f[Vv];
    const float4* fp = reinterpret_cast<const float4*>(F + (long long)t * Vv);
    float4 q0 = fp[0], q1 = fp[1], q2 = fp[2];
    f[0] = q0.x; f[1] = q0.y; f[2]  = q0.z; f[3]  = q0.w;
    f[4] = q1.x; f[5] = q1.y; f[6]  = q1.z; f[7]  = q1.w;
    f[8] = q2.x; f[9] = q2.y; f[10] = q2.z; f[11] = q2.w;

    // Layer-1 factored: h[c](i,j) = lk( W1[c,0]*F[j] + (W1[c,1]*F[i] + b1[c]) )
    float a0[Vv], a1[Vv];
#pragma unroll
    for (int v = 0; v < Vv; ++v) {
        a0[v] = w100 * f[v];
        a1[v] = w110 * f[v];
    }

    float yr[Vv];                 // pre-BN y, kept in registers across the barrier
    float s = 0.f, ss = 0.f;
#pragma unroll
    for (int i = 0; i < Vv; ++i) {
        const float p0i = fmaf(w101, f[i], bb10);
        const float p1i = fmaf(w111, f[i], bb11);
        float ms = 0.f;
#pragma unroll
        for (int j = 0; j < Vv; ++j) {
            float h0 = lk(a0[j] + p0i);
            float h1 = lk(a1[j] + p1i);
            float g0 = lk(fmaf(w200, h0, fmaf(w201, h1, bb20)));
            float g1 = lk(fmaf(w210, h0, fmaf(w211, h1, bb21)));
            ms += lk(fmaf(w30, g0, fmaf(w31, g1, bb3)));
        }
        float yv = fmaf(c0, f[i], fmaf(c1, ms, cbv));
        yr[i] = yv;
        s += yv;
        ss = fmaf(yv, yv, ss);
    }

    // wave(64) shuffle reduction, then block reduction
#pragma unroll
    for (int off = 32; off > 0; off >>= 1) {
        s  += __shfl_down(s,  off, 64);
        ss += __shfl_down(ss, off, 64);
    }
    __shared__ float ls[4], lss[4];
    __shared__ float coef[3];   // scale, mean, shift
    const int lane = threadIdx.x & 63;
    const int wave = threadIdx.x >> 6;
    if (lane == 0) { ls[wave] = s; lss[wave] = ss; }
    __syncthreads();
    if (threadIdx.x == 0) {
        part[2 * blockIdx.x]     = ls[0]  + ls[1]  + ls[2]  + ls[3];
        part[2 * blockIdx.x + 1] = lss[0] + lss[1] + lss[2] + lss[3];
        __threadfence();  // release part[] before the arrival flag
        __hip_atomic_store(&flags[blockIdx.x], TAG,
                           __ATOMIC_RELEASE, __HIP_MEMORY_SCOPE_AGENT);
    }

    // ---- hierarchical grid barrier ----
    if (wave == 0) {
        if (blockIdx.x == 0) {
            // aggregator: 64 lanes x 4 u64 = all 512 arrival flags per round
            const unsigned long long* fl64 =
                reinterpret_cast<const unsigned long long*>(flags);
            bool done;
            do {
                unsigned long long v0 = __hip_atomic_load(&fl64[lane * 4 + 0],
                        __ATOMIC_RELAXED, __HIP_MEMORY_SCOPE_AGENT);
                unsigned long long v1 = __hip_atomic_load(&fl64[lane * 4 + 1],
                        __ATOMIC_RELAXED, __HIP_MEMORY_SCOPE_AGENT);
                unsigned long long v2 = __hip_atomic_load(&fl64[lane * 4 + 2],
                        __ATOMIC_RELAXED, __HIP_MEMORY_SCOPE_AGENT);
                unsigned long long v3 = __hip_atomic_load(&fl64[lane * 4 + 3],
                        __ATOMIC_RELAXED, __HIP_MEMORY_SCOPE_AGENT);
                done = (v0 == TAG2) && (v1 == TAG2) &&
                       (v2 == TAG2) && (v3 == TAG2);
            } while (!__all(done));
            __threadfence();   // acquire all blocks' part[] (device fence)
            if (lane == 0)
                __hip_atomic_store(&flags[512], TAG,
                                   __ATOMIC_RELEASE, __HIP_MEMORY_SCOPE_AGENT);
        } else {
            // one wave per block polls the single DONE flag (relaxed; one
            // coalesced same-line request per round). Fence on exit.
            while (__hip_atomic_load(&flags[512],
                       __ATOMIC_RELAXED, __HIP_MEMORY_SCOPE_AGENT) != TAG) {}
            __threadfence();
        }
    }
    __syncthreads();   // waves 1-3 waited here, issuing nothing

    // ---- phase 2: redundant all-block reduction of the 512 partials.
    // Relaxed agent loads (L1-bypassing) of the 4 KB L2/L3-resident array.
    {
        float pax = __hip_atomic_load(&part[2 * threadIdx.x],
                        __ATOMIC_RELAXED, __HIP_MEMORY_SCOPE_AGENT);
        float pay = __hip_atomic_load(&part[2 * threadIdx.x + 1],
                        __ATOMIC_RELAXED, __HIP_MEMORY_SCOPE_AGENT);
        float pbx = __hip_atomic_load(&part[2 * (threadIdx.x + 256)],
                        __ATOMIC_RELAXED, __HIP_MEMORY_SCOPE_AGENT);
        float pby = __hip_atomic_load(&part[2 * (threadIdx.x + 256) + 1],
                        __ATOMIC_RELAXED, __HIP_MEMORY_SCOPE_AGENT);
        float rs  = pax + pbx;
        float rss = pay + pby;
#pragma unroll
        for (int off = 32; off > 0; off >>= 1) {
            rs  += __shfl_down(rs,  off, 64);
            rss += __shfl_down(rss, off, 64);
        }
        if (lane == 0) { ls[wave] = rs; lss[wave] = rss; }
        __syncthreads();
        if (threadIdx.x == 0) {
            double S  = (double)ls[0]  + ls[1]  + ls[2]  + ls[3];
            double SS = (double)lss[0] + lss[1] + lss[2] + lss[3];
            double mean = S / (double)TOT;
            double var  = SS / (double)TOT - mean * mean;
            coef[0] = (float)(1.0 / sqrt(var + 1e-5)) * gamma[0];
            coef[1] = (float)mean;
            coef[2] = beta[0];
        }
        __syncthreads();
    }
    const float scale = coef[0], mb = coef[1], bt = coef[2];

    const int b = t >> 14;        // / 16384
    const int n = t & (Nn - 1);
#pragma unroll
    for (int i = 0; i < Vv; ++i) {
        // coalesced per i across n; single store pass, post-BN
        y[((long long)b * Vv + i) * Nn + n] = lk(fmaf(yr[i] - mb, scale, bt));
    }
}

extern "C" void kernel_launch(void* const* d_in, const int* in_sizes, int n_in,
                              void* d_out, int out_size, void* d_ws, size_t ws_size,
                              hipStream_t stream) {
    const float* F  = (const float*)d_in[0];
    const float* W1 = (const float*)d_in[1];
    const float* b1 = (const float*)d_in[2];
    const float* W2 = (const float*)d_in[3];
    const float* b2 = (const float*)d_in[4];
    const float* W3 = (const float*)d_in[5];
    const float* b3 = (const float*)d_in[6];
    const float* cw = (const float*)d_in[7];
    const float* cb = (const float*)d_in[8];
    const float* gamma = (const float*)d_in[9];
    const float* beta  = (const float*)d_in[10];

    float* out = (float*)d_out;                        // final output, written once
    float* part = (float*)d_ws;                        // 512 x (sum,sumsq) = 4 KB
    unsigned* flags = (unsigned*)((char*)d_ws + 4096); // 512 arrival + 1 DONE

    nlmp_fused<<<NB1, 256, 0, stream>>>(
        F, W1, b1, W2, b2, W3, b3, cw, cb, gamma, beta, out, part, flags);
}

// Round 4
// 90.236 us; speedup vs baseline: 1.6349x; 1.1541x over previous
//
#include <hip/hip_runtime.h>

// Problem constants (from reference setup_inputs)
constexpr int Bx = 8;
constexpr int Nn = 16384;   // power of two -> shift/mask index math
constexpr int Vv = 12;
constexpr long long TOT = (long long)Bx * Nn * Vv;   // 1,572,864 output elems
constexpr int NB1 = (Bx * Nn) / 256;                 // 512 compute blocks

// Packed fp32 pair (lowers to CDNA VOP3P: v_pk_fma_f32 / v_pk_add_f32 / v_pk_max_f32)
typedef float f32x2 __attribute__((ext_vector_type(2)));

__device__ __forceinline__ float lk(float x) { return fmaxf(x, 0.2f * x); }
__device__ __forceinline__ f32x2 lk2(f32x2 x) {
    return __builtin_elementwise_max(x, 0.2f * x);
}
__device__ __forceinline__ f32x2 fma2(f32x2 a, f32x2 b, f32x2 c) {
    return __builtin_elementwise_fma(a, b, c);
}

// Kernel 1: one thread per (b,n). Pre-BN y[b,v,n] -> y; one float2 partial
// (sum, sumsq) per block -> part. Inner 12x12 relation-MLP packed over
// j-PAIRS (all ops elementwise in j) to halve VALU issue count.
__global__ __launch_bounds__(256) void nlmp_compute(
    const float* __restrict__ F,
    const float* __restrict__ W1, const float* __restrict__ b1,
    const float* __restrict__ W2, const float* __restrict__ b2,
    const float* __restrict__ W3, const float* __restrict__ b3,
    const float* __restrict__ cw, const float* __restrict__ cb,
    float* __restrict__ y, float2* __restrict__ part)
{
    const int t = blockIdx.x * blockDim.x + threadIdx.x;  // in [0, B*N)

    // tiny weight set: broadcast loads, L2/L1 cached
    const float w100 = W1[0], w101 = W1[1], w110 = W1[2], w111 = W1[3];
    const float bb10 = b1[0], bb11 = b1[1];
    const float w200 = W2[0], w201 = W2[1], w210 = W2[2], w211 = W2[3];
    const float bb20 = b2[0], bb21 = b2[1];
    const float w30 = W3[0], w31 = W3[1], bb3 = b3[0];
    const float c0 = cw[0], c1 = cw[1], cbv = cb[0];

    // packed broadcast constants for the inner loop
    const f32x2 W200 = {w200, w200}, W201 = {w201, w201}, BB20 = {bb20, bb20};
    const f32x2 W210 = {w210, w210}, W211 = {w211, w211}, BB21 = {bb21, bb21};
    const f32x2 W30  = {w30,  w30 }, W31  = {w31,  w31 }, BB3  = {bb3,  bb3 };

    // F[b,n,0..11]: contiguous 48 B -> three float4 loads
    float f[Vv];
    const float4* fp = reinterpret_cast<const float4*>(F + (long long)t * Vv);
    float4 q0 = fp[0], q1 = fp[1], q2 = fp[2];
    f[0] = q0.x; f[1] = q0.y; f[2]  = q0.z; f[3]  = q0.w;
    f[4] = q1.x; f[5] = q1.y; f[6]  = q1.z; f[7]  = q1.w;
    f[8] = q2.x; f[9] = q2.y; f[10] = q2.z; f[11] = q2.w;

    // Layer-1 factored: h[c](i,j) = lk( W1[c,0]*F[j] + (W1[c,1]*F[i] + b1[c]) )
    // A0/A1 hold the j-dependent halves as 6 packed pairs.
    f32x2 A0[Vv / 2], A1[Vv / 2];
#pragma unroll
    for (int v = 0; v < Vv / 2; ++v) {
        f32x2 fv = {f[2 * v], f[2 * v + 1]};
        A0[v] = w100 * fv;
        A1[v] = w110 * fv;
    }

    const int b = t >> 14;        // / 16384
    const int n = t & (Nn - 1);

    float s = 0.f, ss = 0.f;
#pragma unroll
    for (int i = 0; i < Vv; ++i) {
        const float p0s = fmaf(w101, f[i], bb10);
        const float p1s = fmaf(w111, f[i], bb11);
        const f32x2 P0 = {p0s, p0s};
        const f32x2 P1 = {p1s, p1s};
        f32x2 acc = {0.f, 0.f};
#pragma unroll
        for (int jp = 0; jp < Vv / 2; ++jp) {
            f32x2 h0 = lk2(A0[jp] + P0);
            f32x2 h1 = lk2(A1[jp] + P1);
            f32x2 g0 = lk2(fma2(W200, h0, fma2(W201, h1, BB20)));
            f32x2 g1 = lk2(fma2(W210, h0, fma2(W211, h1, BB21)));
            acc += lk2(fma2(W30, g0, fma2(W31, g1, BB3)));
        }
        float ms = acc.x + acc.y;
        float yv = fmaf(c0, f[i], fmaf(c1, ms, cbv));
        y[((long long)b * Vv + i) * Nn + n] = yv;   // coalesced per i across n
        s += yv;
        ss = fmaf(yv, yv, ss);
    }

    // wave(64) shuffle reduction, then block reduction, one plain store/block
#pragma unroll
    for (int off = 32; off > 0; off >>= 1) {
        s  += __shfl_down(s,  off, 64);
        ss += __shfl_down(ss, off, 64);
    }
    __shared__ float ls[4], lss[4];
    const int lane = threadIdx.x & 63;
    const int wave = threadIdx.x >> 6;
    if (lane == 0) { ls[wave] = s; lss[wave] = ss; }
    __syncthreads();
    if (threadIdx.x == 0) {
        float2 p;
        p.x = ls[0]  + ls[1]  + ls[2]  + ls[3];
        p.y = lss[0] + lss[1] + lss[2] + lss[3];
        part[blockIdx.x] = p;
    }
}

// Kernel 2: every block redundantly reduces the 512 block-partials (4 KB,
// L2/L3-resident), then applies BN (training-mode batch stats) + leaky in place.
__global__ __launch_bounds__(256) void nlmp_finalize(
    float* __restrict__ y, const float2* __restrict__ part,
    const float* __restrict__ gamma, const float* __restrict__ beta)
{
    const int t = threadIdx.x;

    // reduce 512 partials: thread t handles part[t] and part[t+256]
    float2 pa = part[t], pb = part[t + 256];
    float s  = pa.x + pb.x;
    float ss = pa.y + pb.y;
#pragma unroll
    for (int off = 32; off > 0; off >>= 1) {
        s  += __shfl_down(s,  off, 64);
        ss += __shfl_down(ss, off, 64);
    }
    __shared__ float ls[4], lss[4];
    __shared__ float coef[3];   // scale, mean, shift
    const int lane = t & 63;
    const int wave = t >> 6;
    if (lane == 0) { ls[wave] = s; lss[wave] = ss; }
    __syncthreads();
    if (t == 0) {
        double S  = (double)ls[0]  + ls[1]  + ls[2]  + ls[3];
        double SS = (double)lss[0] + lss[1] + lss[2] + lss[3];
        double mean = S / (double)TOT;
        double var  = SS / (double)TOT - mean * mean;
        coef[0] = (float)(1.0 / sqrt(var + 1e-5)) * gamma[0];
        coef[1] = (float)mean;
        coef[2] = beta[0];
    }
    __syncthreads();
    const float scale = coef[0], mb = coef[1], bt = coef[2];

    const long long idx4 = (long long)blockIdx.x * blockDim.x + t;
    float4 v = reinterpret_cast<float4*>(y)[idx4];
    float4 o;
    o.x = lk(fmaf(v.x - mb, scale, bt));
    o.y = lk(fmaf(v.y - mb, scale, bt));
    o.z = lk(fmaf(v.z - mb, scale, bt));
    o.w = lk(fmaf(v.w - mb, scale, bt));
    reinterpret_cast<float4*>(y)[idx4] = o;
}

extern "C" void kernel_launch(void* const* d_in, const int* in_sizes, int n_in,
                              void* d_out, int out_size, void* d_ws, size_t ws_size,
                              hipStream_t stream) {
    const float* F  = (const float*)d_in[0];
    const float* W1 = (const float*)d_in[1];
    const float* b1 = (const float*)d_in[2];
    const float* W2 = (const float*)d_in[3];
    const float* b2 = (const float*)d_in[4];
    const float* W3 = (const float*)d_in[5];
    const float* b3 = (const float*)d_in[6];
    const float* cw = (const float*)d_in[7];
    const float* cb = (const float*)d_in[8];
    const float* gamma = (const float*)d_in[9];
    const float* beta  = (const float*)d_in[10];

    float*  out  = (float*)d_out;      // pre-BN scratch, finalized in place
    float2* part = (float2*)d_ws;      // 512 block partials (sum, sumsq)

    nlmp_compute<<<NB1, 256, 0, stream>>>(
        F, W1, b1, W2, b2, W3, b3, cw, cb, out, part);

    nlmp_finalize<<<(int)(TOT / 4 / 256), 256, 0, stream>>>(out, part, gamma, beta);
}